// Round 17
// baseline (105.716 us; speedup 1.0000x reference)
//
#include <hip/hip_runtime.h>

#define LPOS 256
#define CCH 20
#define BB 4096
#define LC 5120   // LPOS*CCH

#define QT 512
#define TBL 6400              // 16*20*20 f32 = 25600 B, 1600 quads, 25 segs
#define NCHT 2160             // total 16-wide l2-chunks
#define NBLK 1024
#define NPREPX 9              // extra k_prepare blocks building chunkinfo

// seqC layout: uint4[16][4096] — entry (mw, b) holds bytes s(b, l=16mw..16mw+15).
// chunkinfo[n] = l1 | (m<<8) | (jl<<16) for flat chunk n (sorted by l1).

// ---------------- Kernel 1: seq extraction + linear term + chunk table -----
__global__ __launch_bounds__(256) void k_prepare(
    const float* __restrict__ x_lc, const float* __restrict__ theta_0,
    const float* __restrict__ theta_lc, unsigned char* __restrict__ seqC,
    unsigned* __restrict__ chunkinfo, float* __restrict__ out)
{
    if (blockIdx.x >= BB) {           // chunk-decode table builder blocks
        const int idx = (blockIdx.x - BB) * 256 + threadIdx.x;
        if (idx < NCHT) {
            int T = idx, l1 = 0;
            for (; l1 < 255; ++l1) {
                const int c = 16 - ((l1 + 1) >> 4);
                if (T < c) break;
                T -= c;
            }
            const int m = ((l1 + 1) >> 4) + T;
            const int jl = (m == ((l1 + 1) >> 4)) ? ((l1 + 1) & 15) : 0;
            chunkinfo[idx] = (unsigned)l1 | ((unsigned)m << 8)
                           | ((unsigned)jl << 16);
        }
        return;
    }
    const int b = blockIdx.x;
    const int l = threadIdx.x;
    const float* xp = x_lc + (size_t)b * LC + (size_t)l * CCH;
    const float4* xp4 = reinterpret_cast<const float4*>(xp);
    float v[CCH];
#pragma unroll
    for (int q = 0; q < 5; ++q) {
        float4 t = xp4[q];
        v[q * 4 + 0] = t.x; v[q * 4 + 1] = t.y;
        v[q * 4 + 2] = t.z; v[q * 4 + 3] = t.w;
    }
    int s = 0; float best = v[0];
#pragma unroll
    for (int c = 1; c < CCH; ++c) { if (v[c] > best) { best = v[c]; s = c; } }

    seqC[(size_t)(l >> 4) * (BB * 16) + (size_t)b * 16 + (l & 15)] =
        (unsigned char)s;

    float lin = theta_lc[l * CCH + s];
#pragma unroll
    for (int off = 32; off > 0; off >>= 1) lin += __shfl_down(lin, off, 64);
    __shared__ float partial[4];
    const int wave = threadIdx.x >> 6;
    const int lane = threadIdx.x & 63;
    if (lane == 0) partial[wave] = lin;
    __syncthreads();
    if (threadIdx.x == 0)
        out[b] = theta_0[0] + partial[0] + partial[1] + partial[2] + partial[3];
}

// ---------------- Kernel 2: masked pairwise quadratic form -----------------
// quad[b] = sum_{l1<l2} Theta[l1,s1,l2,s2]. DYNAMIC WORK QUEUE over the
// 2160 flat 16-wide l2-chunks (R14-16 lesson: static partitions of 2160
// across 1024 blocks always leave either empty wave slots or a straggler
// tail; a global atomic counter self-balances to within one solo chunk).
// Per chunk: 16x20x20 f32 table (25 1KB gload_lds segments) staged once,
// then all 4096 batches gathered (thread t: batches i*512+t, i<8).
// Next grab is issued during staging (latency hidden); 2 barriers/chunk.
template <int MODE>
__global__ __launch_bounds__(QT, 8) void k_quad(
    const float* __restrict__ Theta,          // (5120, 5120) f32 row-major
    const uint4* __restrict__ seqC,           // [16][4096]
    const unsigned* __restrict__ chunkinfo,   // [NCHT]
    int* __restrict__ ctr,                    // zeroed before launch
    float* __restrict__ part,                 // [NBLK][4096] (MODE 0)
    float* __restrict__ out)                  // (MODE 1)
{
    __shared__ float Tl[TBL];    // 25.6 KB -> 4 blocks/CU (102.4 KB)
    __shared__ int nn;

    const int tid = threadIdx.x;
    const int wave = tid >> 6;
    const int lane = tid & 63;

    // Stage chunk (l1, m): quad u = seg*64+lane (< 1600 exactly) -> elems
    // 4u..4u+3; r = u/5 (= j*20+s1), cc = u%5 -> Theta row l1*20+s1,
    // cols (16m+j)*20 + 4cc..+3 (16B-aligned, in-row).
    auto stage = [&](int l1, int m) {
#pragma unroll
        for (int k = 0; k < 4; ++k) {
            const int seg = wave + 8 * k;
            if (seg < 25) {
                const int u = seg * 64 + lane;
                const int r = u / 5, cc = u - r * 5;
                const int j = r / CCH, s1 = r - j * CCH;
                const float* gp = Theta + (size_t)(l1 * CCH + s1) * LC
                                        + (m * 16 + j) * CCH + cc * 4;
                float* lp = Tl + seg * 256;
                __builtin_amdgcn_global_load_lds(
                    (const __attribute__((address_space(1))) void*)gp,
                    (__attribute__((address_space(3))) void*)lp, 16, 0, 0);
            }
        }
    };
    // basev[i] = s1(b_i, l1) * 20 from byte (l1&15) of seqC[l1>>4][b_i]
    int basev[8];
    auto loadbase = [&](int l1) {
        const int mw = l1 >> 4;
        const int wsel = (l1 >> 2) & 3;
        const int sh = (l1 & 3) * 8;
#pragma unroll
        for (int i = 0; i < 8; ++i) {
            const uint4 u = seqC[(size_t)mw * BB + i * QT + tid];
            const unsigned w = (wsel == 0) ? u.x : (wsel == 1) ? u.y
                             : (wsel == 2) ? u.z : u.w;
            basev[i] = (int)((w >> sh) & 0xFFu) * CCH;
        }
    };

    float acc[8];
#pragma unroll
    for (int i = 0; i < 8; ++i) acc[i] = 0.f;
    int curl1 = -1;

    if (tid == 0) nn = atomicAdd(ctr, 1);
    __syncthreads();                 // publish first grab
    int n = nn;

    while (n < NCHT) {
        const unsigned info = chunkinfo[n];
        const int l1 = (int)(info & 255u);
        const int m  = (int)((info >> 8) & 15u);
        const int jl = (int)((info >> 16) & 15u);

        stage(l1, m);
        if (l1 != curl1) { loadbase(l1); curl1 = l1; }
        if (tid == 0) nn = atomicAdd(ctr, 1);   // prefetch next grab
        __syncthreads();             // table ready + next grab published

        const size_t mrow = (size_t)m * BB;
        if (jl == 0) {
#pragma unroll
            for (int i = 0; i < 8; ++i) {
                const uint4 u = seqC[mrow + i * QT + tid];   // inline, 1 live
#pragma unroll
                for (int j = 0; j < 16; ++j) {
                    const unsigned w = (j < 4) ? u.x : (j < 8) ? u.y
                                     : (j < 12) ? u.z : u.w;
                    const int s2 = (w >> ((j & 3) * 8)) & 0xFF;
                    acc[i] += Tl[j * 400 + basev[i] + s2];
                }
            }
        } else {            // ragged first chunk of a row (uniform jl)
#pragma unroll
            for (int i = 0; i < 8; ++i) {
                const uint4 u = seqC[mrow + i * QT + tid];
#pragma unroll
                for (int j = 0; j < 16; ++j) {
                    const unsigned w = (j < 4) ? u.x : (j < 8) ? u.y
                                     : (j < 12) ? u.z : u.w;
                    const int s2 = (w >> ((j & 3) * 8)) & 0xFF;
                    const float v = Tl[j * 400 + basev[i] + s2];
                    acc[i] += (j >= jl) ? v : 0.f;
                }
            }
        }
        n = nn;                      // stable since the last barrier
        __syncthreads();             // WAR: gathers done before next stage
    }

    if (MODE == 0) {
        float* row = part + (size_t)blockIdx.x * BB;
#pragma unroll
        for (int i = 0; i < 8; ++i) row[i * QT + tid] = acc[i];
    } else {
#pragma unroll
        for (int i = 0; i < 8; ++i) atomicAdd(&out[i * QT + tid], acc[i]);
    }
}

// ---------------- Kernel 3: reduce partial rows into out -------------------
// grid (4, 64): x -> 256 float4-columns of out, y -> 16 part rows each.
__global__ __launch_bounds__(256) void k_reduce(
    const float4* __restrict__ part4,   // [NBLK][1024]
    float* __restrict__ out)
{
    const int b4 = blockIdx.x * 256 + threadIdx.x;   // < 1024
    const int r0 = blockIdx.y * 16;
    float4 a = make_float4(0.f, 0.f, 0.f, 0.f);
    for (int r = r0; r < r0 + 16; ++r) {
        const float4 p = part4[(size_t)r * 1024 + b4];
        a.x += p.x; a.y += p.y; a.z += p.z; a.w += p.w;
    }
    atomicAdd(&out[b4 * 4 + 0], a.x);
    atomicAdd(&out[b4 * 4 + 1], a.y);
    atomicAdd(&out[b4 * 4 + 2], a.z);
    atomicAdd(&out[b4 * 4 + 3], a.w);
}

extern "C" void kernel_launch(void* const* d_in, const int* in_sizes, int n_in,
                              void* d_out, int out_size, void* d_ws, size_t ws_size,
                              hipStream_t stream) {
    const float* x_lc       = (const float*)d_in[0];
    const float* theta_0    = (const float*)d_in[1];
    const float* theta_lc   = (const float*)d_in[2];
    const float* theta_lclc = (const float*)d_in[3];
    // d_in[4] = mask (bool) — implicit: we only iterate l2 > l1.
    float* out = (float*)d_out;

    unsigned char* seqC = (unsigned char*)d_ws;               // 1 MB
    const size_t part_off = (size_t)1 << 20;
    const size_t part_sz  = (size_t)NBLK * BB * 4;            // 16.78 MB
    const size_t full_ctr_off  = part_off + part_sz;
    const size_t full_info_off = full_ctr_off + 256;
    const size_t need_full = full_info_off + (size_t)NCHT * 4;
    const bool full = (ws_size >= need_full);

    const size_t ctr_off  = full ? full_ctr_off  : part_off;
    const size_t info_off = full ? full_info_off : part_off + 256;

    float*    part      = (float*)((char*)d_ws + part_off);
    int*      ctr       = (int*)((char*)d_ws + ctr_off);
    unsigned* chunkinfo = (unsigned*)((char*)d_ws + info_off);

    hipMemsetAsync(ctr, 0, 4, stream);
    k_prepare<<<dim3(BB + NPREPX), dim3(256), 0, stream>>>(
        x_lc, theta_0, theta_lc, seqC, chunkinfo, out);
    if (full) {
        k_quad<0><<<dim3(NBLK), dim3(QT), 0, stream>>>(
            theta_lclc, (const uint4*)seqC, chunkinfo, ctr, part, out);
        k_reduce<<<dim3(4, 64), dim3(256), 0, stream>>>(
            (const float4*)part, out);
    } else {
        k_quad<1><<<dim3(NBLK), dim3(QT), 0, stream>>>(
            theta_lclc, (const uint4*)seqC, chunkinfo, ctr, part, out);
    }
}